// Round 6
// baseline (9484.296 us; speedup 1.0000x reference)
//
#include <hip/hip_runtime.h>
#include <hip/hip_fp16.h>
#include <cstdint>
#include <cstddef>

typedef _Float16 f16;
typedef __attribute__((ext_vector_type(8))) _Float16 f16x8;
typedef __attribute__((ext_vector_type(4))) _Float16 f16x4;
typedef __attribute__((ext_vector_type(2))) _Float16 f16x2;
typedef __attribute__((ext_vector_type(4))) float f32x4;

#define B_SZ 256
#define T_IN 1024
#define W_CH 512
#define U_N  512
#define P_K  16
#define TP   1009            // T_IN - P_K + 1
#define MROWS (B_SZ * TP)    // 258304

// ---------------------------------------------------------------------------
// Weight convert + transpose: fp32 [k][n] -> f16 [n][k].
// Kt: canonical k order (used by k_gemm).
// Rt: k-axis PERMUTED with pi(k) = (k & ~63) | ((k&15)<<2) | ((k>>4)&3) so the
// rnn state writes to LDS become contiguous stores. MFMA result is invariant
// to a shared k-permutation of A and B.
// ---------------------------------------------------------------------------
__global__ __launch_bounds__(256) void k_convert(
    const float* __restrict__ kern, const float* __restrict__ rec,
    f16* __restrict__ Kt, f16* __restrict__ Rt) {
  int idx = blockIdx.x * 256 + threadIdx.x;   // 0 .. 2*2^18
  int which = idx >> 18;
  int e = idx & 262143;
  int n = e >> 9;
  int k = e & 511;
  if (which == 0) {
    Kt[(size_t)n * 512 + k] = (f16)kern[(size_t)k * 512 + n];
  } else {
    int kp = (k & 448) | ((k & 15) << 2) | ((k >> 4) & 3);
    Rt[(size_t)n * 512 + kp] = (f16)rec[(size_t)k * 512 + n];
  }
}

// ---------------------------------------------------------------------------
// PSC conv: syn[b,t,w] = psc_b + sum_k psc_w[k] * x[b,t+k,w]   (f16 out)
// Thread owns (b, w-quad) and marches 64 t's with a 16-deep float4 ring.
// ---------------------------------------------------------------------------
__global__ __launch_bounds__(256) void k_conv(
    const float* __restrict__ x, const float* __restrict__ psc_w,
    const float* __restrict__ psc_b, f16* __restrict__ syn) {
  int g  = blockIdx.x * 256 + threadIdx.x;
  int wq = g & 127;              // w quad (4 floats)
  int tt = (g >> 7) & 15;        // t tile of 64
  int b  = g >> 11;
  int t0 = tt * 64;
  const float4* xr = (const float4*)x + (size_t)b * T_IN * 128 + wq;
  float wgt[16];
#pragma unroll
  for (int k = 0; k < 16; ++k) wgt[k] = psc_w[k];
  float b0 = psc_b[0];
  float4 win[16];
#pragma unroll
  for (int i = 0; i < 15; ++i) win[i] = xr[(size_t)(t0 + i) * 128];
  f16* sp = syn + ((size_t)b * TP + t0) * 512 + wq * 4;
  int steps = TP - t0; if (steps > 64) steps = 64;   // wave-uniform
  for (int j0 = 0; j0 < 64; j0 += 16) {
#pragma unroll
    for (int jj = 0; jj < 16; ++jj) {
      int j = j0 + jj;
      if (j < steps) {
        win[(j + 15) & 15] = xr[(size_t)(t0 + j + 15) * 128];
        float ax = b0, ay = b0, az = b0, aw = b0;
#pragma unroll
        for (int k = 0; k < 16; ++k) {
          float4 v = win[(j + k) & 15];
          float wk = wgt[k];
          ax += wk * v.x; ay += wk * v.y; az += wk * v.z; aw += wk * v.w;
        }
        f16x4 o; o.x = (f16)ax; o.y = (f16)ay; o.z = (f16)az; o.w = (f16)aw;
        *(f16x4*)(sp + (size_t)j * 512) = o;
      }
    }
  }
}

// ---------------------------------------------------------------------------
// Xp = syn @ K + bias  (fp32 result written into d_out, overwritten later by
// the recurrent kernel in place).  128x128 tile, BK=32, mfma 16x16x32 f16.
// ---------------------------------------------------------------------------
__global__ __launch_bounds__(256) void k_gemm(
    const f16* __restrict__ syn, const f16* __restrict__ Kt,
    const float* __restrict__ bias, float* __restrict__ out) {
  int bid = blockIdx.x;
  size_t m0 = (size_t)(bid >> 2) * 128;
  int n0 = (bid & 3) * 128;
  int tid = threadIdx.x;
  int wave = tid >> 6, lane = tid & 63;
  int q = lane >> 4, l15 = lane & 15;
  __shared__ f16 lA[128 * 32];
  __shared__ f16 lB[128 * 32];
  f32x4 acc[8][2] = {};
  int s0 = tid, s1 = tid + 256;
  int rA0 = s0 >> 2, cA0 = (s0 & 3) * 8;
  int rA1 = s1 >> 2, cA1 = (s1 & 3) * 8;
  for (int k0 = 0; k0 < 512; k0 += 32) {
    f16x8 a0 = *(const f16x8*)(syn + (m0 + rA0) * 512 + k0 + cA0);
    f16x8 a1 = *(const f16x8*)(syn + (m0 + rA1) * 512 + k0 + cA1);
    f16x8 b0 = *(const f16x8*)(Kt + (size_t)(n0 + rA0) * 512 + k0 + cA0);
    f16x8 b1 = *(const f16x8*)(Kt + (size_t)(n0 + rA1) * 512 + k0 + cA1);
    __syncthreads();                       // previous tile fully consumed
    *(f16x8*)(lA + s0 * 8) = a0;  *(f16x8*)(lA + s1 * 8) = a1;
    *(f16x8*)(lB + s0 * 8) = b0;  *(f16x8*)(lB + s1 * 8) = b1;
    __syncthreads();
    f16x8 bf[2];
#pragma unroll
    for (int j = 0; j < 2; ++j)
      bf[j] = *(const f16x8*)(lB + (wave * 32 + j * 16 + l15) * 32 + q * 8);
#pragma unroll
    for (int i = 0; i < 8; ++i) {
      f16x8 af = *(const f16x8*)(lA + (i * 16 + l15) * 32 + q * 8);
      acc[i][0] = __builtin_amdgcn_mfma_f32_16x16x32_f16(af, bf[0], acc[i][0], 0, 0, 0);
      acc[i][1] = __builtin_amdgcn_mfma_f32_16x16x32_f16(af, bf[1], acc[i][1], 0, 0, 0);
    }
  }
#pragma unroll
  for (int j = 0; j < 2; ++j) {
    int col = n0 + wave * 32 + j * 16 + l15;
    float bv = bias[col];
#pragma unroll
    for (int i = 0; i < 8; ++i) {
      size_t row = m0 + i * 16 + q * 4;
#pragma unroll
      for (int r = 0; r < 4; ++r)
        out[(row + r) * 512 + col] = acc[i][j][r] + bv;
    }
  }
}

// ---------------------------------------------------------------------------
// Sequential recurrence.  256 blocks x 1 batch, 512 threads (8 waves, 2/SIMD);
// wave owns 64 output units.  Round-6 structure:
//  (1) FULL R RESIDENCY: rs[16][4] = 256 regs/lane on the unified VGPR/AGPR
//      file (round 4 ran rs[11]=176 with arch VGPR_Count=124 -> headroom;
//      no-spill point is ~450 regs).  No LDS R tile, no L2 stream.
//  (2) EXEC-MASKED af reads: only lanes l15==0 hold real A rows (A layout:
//      row = lane&15, k = (lane>>4)*8+j).  afr[kk] is zeroed once before the
//      loop; per step the loads run under `if (l15==0)` -- a 4-lane
//      exec-masked ds_read_b128 delivers 64B (~1 LDS cy) instead of a 64-lane
//      1KB duplicated read (~8 cy).  Inactive lanes retain zero.
//  (3) Single pass over kk with 4 independent accumulator chains (the
//      round-5 pair split doubled af reads and halved chain parallelism).
// LDS = 2KB state double-buffer only.  One raw s_barrier per step
// (lgkmcnt drain only; global stores are disjoint-address, never drained).
// ---------------------------------------------------------------------------
__global__ __launch_bounds__(512, 2) void k_rnn(
    const f16* __restrict__ Rt, float* __restrict__ io) {
  int b = blockIdx.x;             // one batch per block
  int tid = threadIdx.x, wave = tid >> 6, lane = tid & 63;
  int q = lane >> 4, l15 = lane & 15;
  __shared__ f16 SR[2 * 512];     // state row 0 (pi layout), double-buffered

  if (tid < 512) { SR[tid] = (f16)0.f; SR[512 + tid] = (f16)0.f; }

  // ---- all of R register-resident: rs[16][4] (256 regs, AGPR-eligible) ----
  const f16* rbase = Rt + (size_t)(wave * 64 + l15) * 512 + q * 8;
  f16x8 rs[16][4];
#pragma unroll
  for (int kk = 0; kk < 16; ++kk)
#pragma unroll
    for (int nt = 0; nt < 4; ++nt)
      rs[kk][nt] = *(const f16x8*)(rbase + (size_t)nt * 8192 + kk * 32);

  bool l0 = (l15 == 0);           // lanes carrying real A-row-0 fragments
  bool active = (q == 0);         // lanes carrying real C/D row 0
  f16x8 afr[16];
#pragma unroll
  for (int kk = 0; kk < 16; ++kk) afr[kk] = (f16x8){};   // stays 0 for l15>0

  const f16* pc = SR + q * 8;           // af read base, current state buf
  const f16* pn = SR + 512 + q * 8;     // af read base, next state buf
  f16* wc = SR + 512 + wave * 64 + l15 * 4;  // state write (into next buf)
  f16* wn = SR + wave * 64 + l15 * 4;

  unsigned ioff = (unsigned)b * (TP * 512u) + (unsigned)(wave * 64 + l15);
  float xp[4];
#pragma unroll
  for (int nt = 0; nt < 4; ++nt) xp[nt] = io[ioff + nt * 16u];

  __syncthreads();

  for (int t = 0; t < TP; ++t) {
    // ---- af fragments: 4-lane exec-masked reads, others retain zero ----
    if (l0) {
#pragma unroll
      for (int kk = 0; kk < 16; ++kk)
        afr[kk] = *(const f16x8*)(pc + kk * 32);
    }
    // ---- 64 MFMAs, 4 independent chains, all B-operands in registers ----
    f32x4 acc[4] = {};
#pragma unroll
    for (int kk = 0; kk < 16; ++kk) {
#pragma unroll
      for (int nt = 0; nt < 4; ++nt)
        acc[nt] = __builtin_amdgcn_mfma_f32_16x16x32_f16(afr[kk], rs[kk][nt], acc[nt], 0, 0, 0);
    }
    // ---- epilogue: row 0 only; n -> io, new state -> next buffer ----
    {
      f16x4 sv;
#pragma unroll
      for (int nt = 0; nt < 4; ++nt) {
        float o  = acc[nt][0] + xp[nt];
        float en = __builtin_amdgcn_exp2f(-4.3280850f * o);     // exp(-3o)
        float n  = __builtin_amdgcn_rcpf(1.f + en);             // sigmoid(3o)
        float eg = __builtin_amdgcn_exp2f((2.f * n - 1.f) * 1.4426950f); // exp(2n-1)
        float g  = __builtin_amdgcn_rcpf(1.f + eg);             // sigmoid(1-2n)
        if (active) io[ioff + nt * 16u] = n;                    // n overwrites Xp
        sv[nt] = (f16)(o * g);                                  // new state
      }
      if (active)   // pi layout: unit w*64+nt*16+l15 -> position w*64+l15*4+nt
        *(f16x4*)wc = sv;
    }
    ioff += 512u;
    if (t < TP - 1) {                     // prefetch Xp[t+1]
#pragma unroll
      for (int nt = 0; nt < 4; ++nt) xp[nt] = io[ioff + nt * 16u];
    }
    // Single barrier per step: drain LDS (state write) only; global stores
    // are disjoint-address and never drained in-loop.
    asm volatile("s_waitcnt lgkmcnt(0)\n\ts_barrier" ::: "memory");
    const f16* tp = pc; pc = pn; pn = tp;
    f16* tw = wc; wc = wn; wn = tw;
  }
}

// ---------------------------------------------------------------------------
extern "C" void kernel_launch(void* const* d_in, const int* in_sizes, int n_in,
                              void* d_out, int out_size, void* d_ws, size_t ws_size,
                              hipStream_t stream) {
  (void)in_sizes; (void)n_in; (void)out_size; (void)ws_size;
  const float* x     = (const float*)d_in[0];
  const float* psc_w = (const float*)d_in[1];
  const float* psc_b = (const float*)d_in[2];
  const float* kern  = (const float*)d_in[3];
  const float* rec   = (const float*)d_in[4];
  const float* bias  = (const float*)d_in[5];
  float* out = (float*)d_out;
  char* ws = (char*)d_ws;
  // ws layout: syn f16 (258304*512*2 = 264,503,296 B) | Kt f16 512KB | Rt f16 512KB
  f16* syn = (f16*)ws;
  f16* Kt  = (f16*)(ws + 264503296ull);
  f16* Rt  = (f16*)(ws + 265027584ull);

  k_convert<<<2048, 256, 0, stream>>>(kern, rec, Kt, Rt);
  k_conv   <<<2048, 256, 0, stream>>>(x, psc_w, psc_b, syn);
  k_gemm   <<<2018 * 4, 256, 0, stream>>>(syn, Kt, bias, out);
  k_rnn    <<<256, 512, 0, stream>>>(Rt, out);
}

// Round 7
// 3176.114 us; speedup vs baseline: 2.9861x; 2.9861x over previous
//
#include <hip/hip_runtime.h>
#include <hip/hip_fp16.h>
#include <cstdint>
#include <cstddef>

typedef _Float16 f16;
typedef __attribute__((ext_vector_type(8))) _Float16 f16x8;
typedef __attribute__((ext_vector_type(4))) _Float16 f16x4;
typedef __attribute__((ext_vector_type(4))) float f32x4;

#define B_SZ 256
#define T_IN 1024
#define W_CH 512
#define U_N  512
#define P_K  16
#define TP   1009            // T_IN - P_K + 1
#define MROWS (B_SZ * TP)    // 258304

// ---------------------------------------------------------------------------
// Weight convert + transpose: fp32 [k][n] -> f16 [n][k].
// Kt: canonical k order (used by k_gemm).
// Rt: k-axis PERMUTED with pi(k) = (k & ~63) | ((k&15)<<2) | ((k>>4)&3) so the
// rnn state writes to LDS become contiguous stores. MFMA result is invariant
// to a shared k-permutation of A and B.
// ---------------------------------------------------------------------------
__global__ __launch_bounds__(256) void k_convert(
    const float* __restrict__ kern, const float* __restrict__ rec,
    f16* __restrict__ Kt, f16* __restrict__ Rt) {
  int idx = blockIdx.x * 256 + threadIdx.x;   // 0 .. 2*2^18
  int which = idx >> 18;
  int e = idx & 262143;
  int n = e >> 9;
  int k = e & 511;
  if (which == 0) {
    Kt[(size_t)n * 512 + k] = (f16)kern[(size_t)k * 512 + n];
  } else {
    int kp = (k & 448) | ((k & 15) << 2) | ((k >> 4) & 3);
    Rt[(size_t)n * 512 + kp] = (f16)rec[(size_t)k * 512 + n];
  }
}

// ---------------------------------------------------------------------------
// PSC conv: syn[b,t,w] = psc_b + sum_k psc_w[k] * x[b,t+k,w]   (f16 out)
// Thread owns (b, w-quad) and marches 64 t's with a 16-deep float4 ring.
// ---------------------------------------------------------------------------
__global__ __launch_bounds__(256) void k_conv(
    const float* __restrict__ x, const float* __restrict__ psc_w,
    const float* __restrict__ psc_b, f16* __restrict__ syn) {
  int g  = blockIdx.x * 256 + threadIdx.x;
  int wq = g & 127;              // w quad (4 floats)
  int tt = (g >> 7) & 15;        // t tile of 64
  int b  = g >> 11;
  int t0 = tt * 64;
  const float4* xr = (const float4*)x + (size_t)b * T_IN * 128 + wq;
  float wgt[16];
#pragma unroll
  for (int k = 0; k < 16; ++k) wgt[k] = psc_w[k];
  float b0 = psc_b[0];
  float4 win[16];
#pragma unroll
  for (int i = 0; i < 15; ++i) win[i] = xr[(size_t)(t0 + i) * 128];
  f16* sp = syn + ((size_t)b * TP + t0) * 512 + wq * 4;
  int steps = TP - t0; if (steps > 64) steps = 64;   // wave-uniform
  for (int j0 = 0; j0 < 64; j0 += 16) {
#pragma unroll
    for (int jj = 0; jj < 16; ++jj) {
      int j = j0 + jj;
      if (j < steps) {
        win[(j + 15) & 15] = xr[(size_t)(t0 + j + 15) * 128];
        float ax = b0, ay = b0, az = b0, aw = b0;
#pragma unroll
        for (int k = 0; k < 16; ++k) {
          float4 v = win[(j + k) & 15];
          float wk = wgt[k];
          ax += wk * v.x; ay += wk * v.y; az += wk * v.z; aw += wk * v.w;
        }
        f16x4 o; o.x = (f16)ax; o.y = (f16)ay; o.z = (f16)az; o.w = (f16)aw;
        *(f16x4*)(sp + (size_t)j * 512) = o;
      }
    }
  }
}

// ---------------------------------------------------------------------------
// Xp = syn @ K + bias  (fp32 result written into d_out, overwritten later by
// the recurrent kernel in place).  128x128 tile, BK=32, mfma 16x16x32 f16.
// ---------------------------------------------------------------------------
__global__ __launch_bounds__(256) void k_gemm(
    const f16* __restrict__ syn, const f16* __restrict__ Kt,
    const float* __restrict__ bias, float* __restrict__ out) {
  int bid = blockIdx.x;
  size_t m0 = (size_t)(bid >> 2) * 128;
  int n0 = (bid & 3) * 128;
  int tid = threadIdx.x;
  int wave = tid >> 6, lane = tid & 63;
  int q = lane >> 4, l15 = lane & 15;
  __shared__ f16 lA[128 * 32];
  __shared__ f16 lB[128 * 32];
  f32x4 acc[8][2] = {};
  int s0 = tid, s1 = tid + 256;
  int rA0 = s0 >> 2, cA0 = (s0 & 3) * 8;
  int rA1 = s1 >> 2, cA1 = (s1 & 3) * 8;
  for (int k0 = 0; k0 < 512; k0 += 32) {
    f16x8 a0 = *(const f16x8*)(syn + (m0 + rA0) * 512 + k0 + cA0);
    f16x8 a1 = *(const f16x8*)(syn + (m0 + rA1) * 512 + k0 + cA1);
    f16x8 b0 = *(const f16x8*)(Kt + (size_t)(n0 + rA0) * 512 + k0 + cA0);
    f16x8 b1 = *(const f16x8*)(Kt + (size_t)(n0 + rA1) * 512 + k0 + cA1);
    __syncthreads();                       // previous tile fully consumed
    *(f16x8*)(lA + s0 * 8) = a0;  *(f16x8*)(lA + s1 * 8) = a1;
    *(f16x8*)(lB + s0 * 8) = b0;  *(f16x8*)(lB + s1 * 8) = b1;
    __syncthreads();
    f16x8 bf[2];
#pragma unroll
    for (int j = 0; j < 2; ++j)
      bf[j] = *(const f16x8*)(lB + (wave * 32 + j * 16 + l15) * 32 + q * 8);
#pragma unroll
    for (int i = 0; i < 8; ++i) {
      f16x8 af = *(const f16x8*)(lA + (i * 16 + l15) * 32 + q * 8);
      acc[i][0] = __builtin_amdgcn_mfma_f32_16x16x32_f16(af, bf[0], acc[i][0], 0, 0, 0);
      acc[i][1] = __builtin_amdgcn_mfma_f32_16x16x32_f16(af, bf[1], acc[i][1], 0, 0, 0);
    }
  }
#pragma unroll
  for (int j = 0; j < 2; ++j) {
    int col = n0 + wave * 32 + j * 16 + l15;
    float bv = bias[col];
#pragma unroll
    for (int i = 0; i < 8; ++i) {
      size_t row = m0 + i * 16 + q * 4;
#pragma unroll
      for (int r = 0; r < 4; ++r)
        out[(row + r) * 512 + col] = acc[i][j][r] + bv;
    }
  }
}

// ---------------------------------------------------------------------------
// Sequential recurrence.  256 blocks x 1 batch, 512 threads (8 waves, 2/SIMD);
// wave owns 64 output units.  Round-7 structure (= round 4 + masked af reads,
// register-safe):
//  - R split: kk0..11 register/AGPR-resident (rs[12][4] = 192 regs -- under
//    the 256/wave cap so the compiler does NOT rematerialize; round 6's
//    rs[16] attempt remat'd and re-streamed 512KB/step from L2/HBM).
//    kk12..15 in a 128KB swizzled LDS tile.  NO in-loop L2 stream.
//  - af path: EXEC-MASKED reads.  Only lanes l15==0 carry real A rows; the
//    reads run under if(l15==0) into double-buffered afr windows of 4
//    (window g+1 read while group g's MFMAs issue).  Inactive lanes are
//    zero-initialized once and never written.  This removes the 64-lane
//    broadcast av-reads that rounds 3-5 showed cost ~17cy each and generated
//    the invariant 1.32e8 bank-conflict count (round 6: conflicts == 0).
//  - State: only row 0 real -> 2KB double-buffered SR, f16x4 pi-layout write.
// One raw s_barrier per step (lgkmcnt drain only; global stores are
// disjoint-address, never drained in-loop).
// ---------------------------------------------------------------------------
__global__ __launch_bounds__(512, 2) void k_rnn(
    const f16* __restrict__ Rt, float* __restrict__ io) {
  int b = blockIdx.x;             // one batch per block
  int tid = threadIdx.x, wave = tid >> 6, lane = tid & 63;
  int q = lane >> 4, l15 = lane & 15;
  __shared__ f16 R4[4 * 512 * 32];   // kk 12..15, [g][row][32k], swizzled (128KB)
  __shared__ f16 SR[2 * 512];        // state row 0 (pi layout), double-buffered

  // ---- stage R kk12..15 into LDS, swizzle: 16B slot c -> c ^ (row&3) ----
  {
    int row = tid;                   // 0..511
    const f16x8* src = (const f16x8*)(Rt + (size_t)row * 512 + 12 * 32);
#pragma unroll
    for (int g = 0; g < 4; ++g) {
      char* dst = (char*)R4 + g * 32768 + row * 64;
#pragma unroll
      for (int c = 0; c < 4; ++c)
        *(f16x8*)(dst + ((c * 16) ^ ((row & 3) << 4))) = src[g * 4 + c];
    }
    if (tid < 512) { SR[tid] = (f16)0.f; SR[512 + tid] = (f16)0.f; }
  }

  // ---- kk0..11 register-resident (192 regs, AGPR-eligible) ----
  const f16* rbase = Rt + (size_t)(wave * 64 + l15) * 512 + q * 8;
  f16x8 rs[12][4];
#pragma unroll
  for (int kk = 0; kk < 12; ++kk)
#pragma unroll
    for (int nt = 0; nt < 4; ++nt)
      rs[kk][nt] = *(const f16x8*)(rbase + (size_t)nt * 8192 + kk * 32);

  // per-lane R4 read base: row = wave*64 + l15 (+nt*16), slot q ^ (l15&3)
  const char* r4base = (const char*)R4 + (wave * 64 + l15) * 64
                       + ((q * 16) ^ ((l15 & 3) << 4));

  bool l0 = (l15 == 0);           // lanes carrying real A-row-0 fragments
  bool active = (q == 0);         // lanes carrying real C/D row 0

  f16x8 afrA[4], afrB[4];         // masked-read double buffer (32 regs)
#pragma unroll
  for (int i = 0; i < 4; ++i) { afrA[i] = (f16x8){}; afrB[i] = (f16x8){}; }

  const f16* pc = SR + q * 8;           // af read base, current state buf
  const f16* pn = SR + 512 + q * 8;     // af read base, next state buf
  f16* wc = SR + 512 + wave * 64 + l15 * 4;  // state write (into next buf)
  f16* wn = SR + wave * 64 + l15 * 4;

  unsigned ioff = (unsigned)b * (TP * 512u) + (unsigned)(wave * 64 + l15);
  float xp[4];
#pragma unroll
  for (int nt = 0; nt < 4; ++nt) xp[nt] = io[ioff + nt * 16u];

  __syncthreads();

  for (int t = 0; t < TP; ++t) {
    f32x4 acc[4] = {};
    // ---- window 0: kk0-3 -> afrA ----
    if (l0) {
#pragma unroll
      for (int i = 0; i < 4; ++i) afrA[i] = *(const f16x8*)(pc + i * 32);
    }
    // ---- read kk4-7 -> afrB, MFMA kk0-3 (rs) ----
    if (l0) {
#pragma unroll
      for (int i = 0; i < 4; ++i) afrB[i] = *(const f16x8*)(pc + (4 + i) * 32);
    }
#pragma unroll
    for (int kk = 0; kk < 4; ++kk)
#pragma unroll
      for (int nt = 0; nt < 4; ++nt)
        acc[nt] = __builtin_amdgcn_mfma_f32_16x16x32_f16(afrA[kk], rs[kk][nt], acc[nt], 0, 0, 0);
    // ---- read kk8-11 -> afrA, MFMA kk4-7 (rs) ----
    if (l0) {
#pragma unroll
      for (int i = 0; i < 4; ++i) afrA[i] = *(const f16x8*)(pc + (8 + i) * 32);
    }
#pragma unroll
    for (int kk = 4; kk < 8; ++kk)
#pragma unroll
      for (int nt = 0; nt < 4; ++nt)
        acc[nt] = __builtin_amdgcn_mfma_f32_16x16x32_f16(afrB[kk - 4], rs[kk][nt], acc[nt], 0, 0, 0);
    // ---- read kk12-15 -> afrB, MFMA kk8-11 (rs) ----
    if (l0) {
#pragma unroll
      for (int i = 0; i < 4; ++i) afrB[i] = *(const f16x8*)(pc + (12 + i) * 32);
    }
#pragma unroll
    for (int kk = 8; kk < 12; ++kk)
#pragma unroll
      for (int nt = 0; nt < 4; ++nt)
        acc[nt] = __builtin_amdgcn_mfma_f32_16x16x32_f16(afrA[kk - 8], rs[kk][nt], acc[nt], 0, 0, 0);
    // ---- MFMA kk12-15: B from R4 LDS tile (swizzled) ----
#pragma unroll
    for (int g = 0; g < 4; ++g) {
      f16x8 bf[4];
#pragma unroll
      for (int nt = 0; nt < 4; ++nt)
        bf[nt] = *(const f16x8*)(r4base + g * 32768 + nt * 1024);
#pragma unroll
      for (int nt = 0; nt < 4; ++nt)
        acc[nt] = __builtin_amdgcn_mfma_f32_16x16x32_f16(afrB[g], bf[nt], acc[nt], 0, 0, 0);
    }
    // ---- epilogue: row 0 only; n -> io, new state -> next buffer ----
    {
      f16x4 sv;
#pragma unroll
      for (int nt = 0; nt < 4; ++nt) {
        float o  = acc[nt][0] + xp[nt];
        float en = __builtin_amdgcn_exp2f(-4.3280850f * o);     // exp(-3o)
        float n  = __builtin_amdgcn_rcpf(1.f + en);             // sigmoid(3o)
        float eg = __builtin_amdgcn_exp2f((2.f * n - 1.f) * 1.4426950f); // exp(2n-1)
        float g  = __builtin_amdgcn_rcpf(1.f + eg);             // sigmoid(1-2n)
        if (active) io[ioff + nt * 16u] = n;                    // n overwrites Xp
        sv[nt] = (f16)(o * g);                                  // new state
      }
      if (active)   // pi layout: unit w*64+nt*16+l15 -> position w*64+l15*4+nt
        *(f16x4*)wc = sv;
    }
    ioff += 512u;
    if (t < TP - 1) {                     // prefetch Xp[t+1]
#pragma unroll
      for (int nt = 0; nt < 4; ++nt) xp[nt] = io[ioff + nt * 16u];
    }
    // Single barrier per step: drain LDS (state write) only; global stores
    // are disjoint-address and never drained in-loop.
    asm volatile("s_waitcnt lgkmcnt(0)\n\ts_barrier" ::: "memory");
    const f16* tp = pc; pc = pn; pn = tp;
    f16* tw = wc; wc = wn; wn = tw;
  }
}

// ---------------------------------------------------------------------------
extern "C" void kernel_launch(void* const* d_in, const int* in_sizes, int n_in,
                              void* d_out, int out_size, void* d_ws, size_t ws_size,
                              hipStream_t stream) {
  (void)in_sizes; (void)n_in; (void)out_size; (void)ws_size;
  const float* x     = (const float*)d_in[0];
  const float* psc_w = (const float*)d_in[1];
  const float* psc_b = (const float*)d_in[2];
  const float* kern  = (const float*)d_in[3];
  const float* rec   = (const float*)d_in[4];
  const float* bias  = (const float*)d_in[5];
  float* out = (float*)d_out;
  char* ws = (char*)d_ws;
  // ws layout: syn f16 (258304*512*2 = 264,503,296 B) | Kt f16 512KB | Rt f16 512KB
  f16* syn = (f16*)ws;
  f16* Kt  = (f16*)(ws + 264503296ull);
  f16* Rt  = (f16*)(ws + 265027584ull);

  k_convert<<<2048, 256, 0, stream>>>(kern, rec, Kt, Rt);
  k_conv   <<<2048, 256, 0, stream>>>(x, psc_w, psc_b, syn);
  k_gemm   <<<2018 * 4, 256, 0, stream>>>(syn, Kt, bias, out);
  k_rnn    <<<256, 512, 0, stream>>>(Rt, out);
}

// Round 8
// 3008.536 us; speedup vs baseline: 3.1525x; 1.0557x over previous
//
#include <hip/hip_runtime.h>
#include <hip/hip_fp16.h>
#include <cstdint>
#include <cstddef>

typedef _Float16 f16;
typedef __attribute__((ext_vector_type(8))) _Float16 f16x8;
typedef __attribute__((ext_vector_type(4))) _Float16 f16x4;
typedef __attribute__((ext_vector_type(4))) float f32x4;
typedef __attribute__((ext_vector_type(4))) unsigned int u32x4;

#define B_SZ 256
#define T_IN 1024
#define W_CH 512
#define U_N  512
#define P_K  16
#define TP   1009            // T_IN - P_K + 1
#define MROWS (B_SZ * TP)    // 258304

// ---------------------------------------------------------------------------
// Weight convert + transpose: fp32 [k][n] -> f16 [n][k].
// Kt: canonical k order (used by k_gemm).
// Rt: k-axis PERMUTED with pi(k) = (k & ~63) | ((k&15)<<2) | ((k>>4)&3) so the
// rnn state writes to LDS become contiguous stores. MFMA result is invariant
// to a shared k-permutation of A and B.
// ---------------------------------------------------------------------------
__global__ __launch_bounds__(256) void k_convert(
    const float* __restrict__ kern, const float* __restrict__ rec,
    f16* __restrict__ Kt, f16* __restrict__ Rt) {
  int idx = blockIdx.x * 256 + threadIdx.x;   // 0 .. 2*2^18
  int which = idx >> 18;
  int e = idx & 262143;
  int n = e >> 9;
  int k = e & 511;
  if (which == 0) {
    Kt[(size_t)n * 512 + k] = (f16)kern[(size_t)k * 512 + n];
  } else {
    int kp = (k & 448) | ((k & 15) << 2) | ((k >> 4) & 3);
    Rt[(size_t)n * 512 + kp] = (f16)rec[(size_t)k * 512 + n];
  }
}

// ---------------------------------------------------------------------------
// PSC conv: syn[b,t,w] = psc_b + sum_k psc_w[k] * x[b,t+k,w]   (f16 out)
// Thread owns (b, w-quad) and marches 64 t's with a 16-deep float4 ring.
// ---------------------------------------------------------------------------
__global__ __launch_bounds__(256) void k_conv(
    const float* __restrict__ x, const float* __restrict__ psc_w,
    const float* __restrict__ psc_b, f16* __restrict__ syn) {
  int g  = blockIdx.x * 256 + threadIdx.x;
  int wq = g & 127;              // w quad (4 floats)
  int tt = (g >> 7) & 15;        // t tile of 64
  int b  = g >> 11;
  int t0 = tt * 64;
  const float4* xr = (const float4*)x + (size_t)b * T_IN * 128 + wq;
  float wgt[16];
#pragma unroll
  for (int k = 0; k < 16; ++k) wgt[k] = psc_w[k];
  float b0 = psc_b[0];
  float4 win[16];
#pragma unroll
  for (int i = 0; i < 15; ++i) win[i] = xr[(size_t)(t0 + i) * 128];
  f16* sp = syn + ((size_t)b * TP + t0) * 512 + wq * 4;
  int steps = TP - t0; if (steps > 64) steps = 64;   // wave-uniform
  for (int j0 = 0; j0 < 64; j0 += 16) {
#pragma unroll
    for (int jj = 0; jj < 16; ++jj) {
      int j = j0 + jj;
      if (j < steps) {
        win[(j + 15) & 15] = xr[(size_t)(t0 + j + 15) * 128];
        float ax = b0, ay = b0, az = b0, aw = b0;
#pragma unroll
        for (int k = 0; k < 16; ++k) {
          float4 v = win[(j + k) & 15];
          float wk = wgt[k];
          ax += wk * v.x; ay += wk * v.y; az += wk * v.z; aw += wk * v.w;
        }
        f16x4 o; o.x = (f16)ax; o.y = (f16)ay; o.z = (f16)az; o.w = (f16)aw;
        *(f16x4*)(sp + (size_t)j * 512) = o;
      }
    }
  }
}

// ---------------------------------------------------------------------------
// Xp = syn @ K + bias  (fp32 result written into d_out, overwritten later by
// the recurrent kernel in place).  128x128 tile, BK=32, mfma 16x16x32 f16.
// ---------------------------------------------------------------------------
__global__ __launch_bounds__(256) void k_gemm(
    const f16* __restrict__ syn, const f16* __restrict__ Kt,
    const float* __restrict__ bias, float* __restrict__ out) {
  int bid = blockIdx.x;
  size_t m0 = (size_t)(bid >> 2) * 128;
  int n0 = (bid & 3) * 128;
  int tid = threadIdx.x;
  int wave = tid >> 6, lane = tid & 63;
  int q = lane >> 4, l15 = lane & 15;
  __shared__ f16 lA[128 * 32];
  __shared__ f16 lB[128 * 32];
  f32x4 acc[8][2] = {};
  int s0 = tid, s1 = tid + 256;
  int rA0 = s0 >> 2, cA0 = (s0 & 3) * 8;
  int rA1 = s1 >> 2, cA1 = (s1 & 3) * 8;
  for (int k0 = 0; k0 < 512; k0 += 32) {
    f16x8 a0 = *(const f16x8*)(syn + (m0 + rA0) * 512 + k0 + cA0);
    f16x8 a1 = *(const f16x8*)(syn + (m0 + rA1) * 512 + k0 + cA1);
    f16x8 b0 = *(const f16x8*)(Kt + (size_t)(n0 + rA0) * 512 + k0 + cA0);
    f16x8 b1 = *(const f16x8*)(Kt + (size_t)(n0 + rA1) * 512 + k0 + cA1);
    __syncthreads();                       // previous tile fully consumed
    *(f16x8*)(lA + s0 * 8) = a0;  *(f16x8*)(lA + s1 * 8) = a1;
    *(f16x8*)(lB + s0 * 8) = b0;  *(f16x8*)(lB + s1 * 8) = b1;
    __syncthreads();
    f16x8 bf[2];
#pragma unroll
    for (int j = 0; j < 2; ++j)
      bf[j] = *(const f16x8*)(lB + (wave * 32 + j * 16 + l15) * 32 + q * 8);
#pragma unroll
    for (int i = 0; i < 8; ++i) {
      f16x8 af = *(const f16x8*)(lA + (i * 16 + l15) * 32 + q * 8);
      acc[i][0] = __builtin_amdgcn_mfma_f32_16x16x32_f16(af, bf[0], acc[i][0], 0, 0, 0);
      acc[i][1] = __builtin_amdgcn_mfma_f32_16x16x32_f16(af, bf[1], acc[i][1], 0, 0, 0);
    }
  }
#pragma unroll
  for (int j = 0; j < 2; ++j) {
    int col = n0 + wave * 32 + j * 16 + l15;
    float bv = bias[col];
#pragma unroll
    for (int i = 0; i < 8; ++i) {
      size_t row = m0 + i * 16 + q * 4;
#pragma unroll
      for (int r = 0; r < 4; ++r)
        out[(row + r) * 512 + col] = acc[i][j][r] + bv;
    }
  }
}

// ---------------------------------------------------------------------------
// Sequential recurrence.  256 blocks x 1 batch, 512 threads (8 waves, 2/SIMD);
// wave owns 64 output units.  Round-8 = round-4 structure with the B-operand
// byte split rebalanced (LDS bandwidth is the measured binder: R4's step
// 1,313cy ~= 128KB/step tile traffic at 128B/cy):
//  - rs[12][4]: kk0..11 register/AGPR-resident (192 regs; R7 proved no
//    rematerialization at this size -- R6's rs[16] remat'd to 25GB FETCH).
//  - R4 tile: kk12..14 only (96KB, swizzled) -> LDS B-traffic 128->96KB/step.
//  - kk15 streamed from L2 (32KB/step on the VMEM pipe, issued at step-top,
//    consumed last -- the R4-proven overlap).
//  - af path: R4's broadcast read + amask (same-address lanes broadcast free;
//    R5/R7 proved masked/zero-region variants are neutral-to-worse).
//  - 4 independent accumulator chains (R5's 2-chain split stalls the MFMA
//    pipe: 2x4.85cy issue < MFMA latency).
//  - State: row 0 only, 2KB double-buffered SR, f16x4 pi-layout write.
// One raw s_barrier per step (lgkmcnt drain only; global stores are
// disjoint-address, never drained in-loop).
// NOTE: SQ_LDS_BANK_CONFLICT ~1e8 here is a counter artifact of multi-phase
// b128 tile reads (R4=R5=R7 identical count, R6=0); timing-neutral.
// ---------------------------------------------------------------------------
__global__ __launch_bounds__(512, 2) void k_rnn(
    const f16* __restrict__ Rt, float* __restrict__ io) {
  int b = blockIdx.x;             // one batch per block
  int tid = threadIdx.x, wave = tid >> 6, lane = tid & 63;
  int q = lane >> 4, l15 = lane & 15;
  __shared__ f16 R4[3 * 512 * 32];   // kk 12..14, [g][row][32k], swizzled (96KB)
  __shared__ f16 SR[2 * 512];        // state row 0 (pi layout), double-buffered

  // ---- stage R kk12..14 into LDS, swizzle: 16B slot c -> c ^ (row&3) ----
  {
    int row = tid;                   // 0..511
    const f16x8* src = (const f16x8*)(Rt + (size_t)row * 512 + 12 * 32);
#pragma unroll
    for (int g = 0; g < 3; ++g) {
      char* dst = (char*)R4 + g * 32768 + row * 64;
#pragma unroll
      for (int c = 0; c < 4; ++c)
        *(f16x8*)(dst + ((c * 16) ^ ((row & 3) << 4))) = src[g * 4 + c];
    }
    if (tid < 512) { SR[tid] = (f16)0.f; SR[512 + tid] = (f16)0.f; }
  }

  // ---- kk0..11 register-resident (192 regs, AGPR-eligible) ----
  const f16* rbase = Rt + (size_t)(wave * 64 + l15) * 512 + q * 8;
  f16x8 rs[12][4];
#pragma unroll
  for (int kk = 0; kk < 12; ++kk)
#pragma unroll
    for (int nt = 0; nt < 4; ++nt)
      rs[kk][nt] = *(const f16x8*)(rbase + (size_t)nt * 8192 + kk * 32);

  unsigned amask = (l15 == 0) ? 0xFFFFFFFFu : 0u;   // A-row mask (rows 1-15 = 0)
  // per-lane R4 read base: row = wave*64 + l15 (+nt*16), slot q ^ (l15&3)
  const char* r4base = (const char*)R4 + (wave * 64 + l15) * 64
                       + ((q * 16) ^ ((l15 & 3) << 4));

  bool active = (q == 0);         // only C/D row 0 is real
  unsigned ioff = (unsigned)b * (TP * 512u) + (unsigned)(wave * 64 + l15);
  float xp[4];
#pragma unroll
  for (int nt = 0; nt < 4; ++nt) xp[nt] = io[ioff + nt * 16u];

  int sel = 0;
  __syncthreads();

  for (int t = 0; t < TP; ++t) {
    const f16* sb = SR + sel * 512;
    f32x4 acc[4] = {};
    // ---- issue kk15 L2 stream at step-top (consumed last: ~full step away)
    f16x8 sw[4];
#pragma unroll
    for (int nt = 0; nt < 4; ++nt)
      sw[nt] = *(const f16x8*)(rbase + (size_t)nt * 8192 + 15 * 32);
    // ---- kk 0..11: broadcast af + register-resident B ----
#pragma unroll
    for (int kk = 0; kk < 12; ++kk) {
      f16x8 av = *(const f16x8*)(sb + kk * 32 + q * 8);
      u32x4 ab = *(u32x4*)&av;  ab &= amask;
      f16x8 af = *(f16x8*)&ab;
#pragma unroll
      for (int nt = 0; nt < 4; ++nt)
        acc[nt] = __builtin_amdgcn_mfma_f32_16x16x32_f16(af, rs[kk][nt], acc[nt], 0, 0, 0);
    }
    // ---- kk 12..14: B from LDS tile (swizzled) ----
#pragma unroll
    for (int g = 0; g < 3; ++g) {
      f16x8 bf[4];
#pragma unroll
      for (int nt = 0; nt < 4; ++nt)
        bf[nt] = *(const f16x8*)(r4base + g * 32768 + nt * 1024);
      f16x8 av = *(const f16x8*)(sb + (12 + g) * 32 + q * 8);
      u32x4 ab = *(u32x4*)&av;  ab &= amask;
      f16x8 af = *(f16x8*)&ab;
#pragma unroll
      for (int nt = 0; nt < 4; ++nt)
        acc[nt] = __builtin_amdgcn_mfma_f32_16x16x32_f16(af, bf[nt], acc[nt], 0, 0, 0);
    }
    // ---- kk 15: streamed B ----
    {
      f16x8 av = *(const f16x8*)(sb + 15 * 32 + q * 8);
      u32x4 ab = *(u32x4*)&av;  ab &= amask;
      f16x8 af = *(f16x8*)&ab;
#pragma unroll
      for (int nt = 0; nt < 4; ++nt)
        acc[nt] = __builtin_amdgcn_mfma_f32_16x16x32_f16(af, sw[nt], acc[nt], 0, 0, 0);
    }
    // ---- epilogue: row 0 only; n -> io, new state -> SR[sel^1] ----
    f16* sn = SR + (sel ^ 1) * 512;
    {
      f16x4 sv;
#pragma unroll
      for (int nt = 0; nt < 4; ++nt) {
        float o  = acc[nt][0] + xp[nt];
        float en = __builtin_amdgcn_exp2f(-4.3280850f * o);     // exp(-3o)
        float n  = __builtin_amdgcn_rcpf(1.f + en);             // sigmoid(3o)
        float eg = __builtin_amdgcn_exp2f((2.f * n - 1.f) * 1.4426950f); // exp(2n-1)
        float g  = __builtin_amdgcn_rcpf(1.f + eg);             // sigmoid(1-2n)
        if (active) io[ioff + nt * 16u] = n;                    // n overwrites Xp
        sv[nt] = (f16)(o * g);                                  // new state
      }
      if (active)   // pi layout: unit w*64+nt*16+l15 -> position w*64+l15*4+nt
        *(f16x4*)(sn + wave * 64 + l15 * 4) = sv;
    }
    ioff += 512u;
    if (t < TP - 1) {                     // prefetch Xp[t+1]
#pragma unroll
      for (int nt = 0; nt < 4; ++nt) xp[nt] = io[ioff + nt * 16u];
    }
    // Single barrier per step: drain LDS (state write) only; global stores
    // are disjoint-address and never drained in-loop.
    asm volatile("s_waitcnt lgkmcnt(0)\n\ts_barrier" ::: "memory");
    sel ^= 1;
  }
}

// ---------------------------------------------------------------------------
extern "C" void kernel_launch(void* const* d_in, const int* in_sizes, int n_in,
                              void* d_out, int out_size, void* d_ws, size_t ws_size,
                              hipStream_t stream) {
  (void)in_sizes; (void)n_in; (void)out_size; (void)ws_size;
  const float* x     = (const float*)d_in[0];
  const float* psc_w = (const float*)d_in[1];
  const float* psc_b = (const float*)d_in[2];
  const float* kern  = (const float*)d_in[3];
  const float* rec   = (const float*)d_in[4];
  const float* bias  = (const float*)d_in[5];
  float* out = (float*)d_out;
  char* ws = (char*)d_ws;
  // ws layout: syn f16 (258304*512*2 = 264,503,296 B) | Kt f16 512KB | Rt f16 512KB
  f16* syn = (f16*)ws;
  f16* Kt  = (f16*)(ws + 264503296ull);
  f16* Rt  = (f16*)(ws + 265027584ull);

  k_convert<<<2048, 256, 0, stream>>>(kern, rec, Kt, Rt);
  k_conv   <<<2048, 256, 0, stream>>>(x, psc_w, psc_b, syn);
  k_gemm   <<<2018 * 4, 256, 0, stream>>>(syn, Kt, bias, out);
  k_rnn    <<<256, 512, 0, stream>>>(Rt, out);
}

// Round 9
// 2606.704 us; speedup vs baseline: 3.6384x; 1.1542x over previous
//
#include <hip/hip_runtime.h>
#include <hip/hip_fp16.h>
#include <cstdint>
#include <cstddef>

typedef _Float16 f16;
typedef __attribute__((ext_vector_type(8))) _Float16 f16x8;
typedef __attribute__((ext_vector_type(4))) _Float16 f16x4;
typedef __attribute__((ext_vector_type(2))) _Float16 f16x2;
typedef __attribute__((ext_vector_type(4))) float f32x4;

#define B_SZ 256
#define T_IN 1024
#define W_CH 512
#define U_N  512
#define P_K  16
#define TP   1009            // T_IN - P_K + 1
#define MROWS (B_SZ * TP)    // 258304

// ---------------------------------------------------------------------------
// Weight convert + transpose: fp32 [k][n] -> f16 [n][k].
// Kt: canonical k order (used by k_gemm).
// Rt: k-axis PERMUTED with pi(k) = (k & ~63) | ((k&15)<<2) | ((k>>4)&3) so the
// rnn state writes to LDS become contiguous stores. MFMA result is invariant
// to a shared k-permutation of A and B.
// ---------------------------------------------------------------------------
__global__ __launch_bounds__(256) void k_convert(
    const float* __restrict__ kern, const float* __restrict__ rec,
    f16* __restrict__ Kt, f16* __restrict__ Rt) {
  int idx = blockIdx.x * 256 + threadIdx.x;   // 0 .. 2*2^18
  int which = idx >> 18;
  int e = idx & 262143;
  int n = e >> 9;
  int k = e & 511;
  if (which == 0) {
    Kt[(size_t)n * 512 + k] = (f16)kern[(size_t)k * 512 + n];
  } else {
    int kp = (k & 448) | ((k & 15) << 2) | ((k >> 4) & 3);
    Rt[(size_t)n * 512 + kp] = (f16)rec[(size_t)k * 512 + n];
  }
}

// ---------------------------------------------------------------------------
// PSC conv: syn[b,t,w] = psc_b + sum_k psc_w[k] * x[b,t+k,w]   (f16 out)
// Thread owns (b, w-quad) and marches 64 t's with a 16-deep float4 ring.
// ---------------------------------------------------------------------------
__global__ __launch_bounds__(256) void k_conv(
    const float* __restrict__ x, const float* __restrict__ psc_w,
    const float* __restrict__ psc_b, f16* __restrict__ syn) {
  int g  = blockIdx.x * 256 + threadIdx.x;
  int wq = g & 127;              // w quad (4 floats)
  int tt = (g >> 7) & 15;        // t tile of 64
  int b  = g >> 11;
  int t0 = tt * 64;
  const float4* xr = (const float4*)x + (size_t)b * T_IN * 128 + wq;
  float wgt[16];
#pragma unroll
  for (int k = 0; k < 16; ++k) wgt[k] = psc_w[k];
  float b0 = psc_b[0];
  float4 win[16];
#pragma unroll
  for (int i = 0; i < 15; ++i) win[i] = xr[(size_t)(t0 + i) * 128];
  f16* sp = syn + ((size_t)b * TP + t0) * 512 + wq * 4;
  int steps = TP - t0; if (steps > 64) steps = 64;   // wave-uniform
  for (int j0 = 0; j0 < 64; j0 += 16) {
#pragma unroll
    for (int jj = 0; jj < 16; ++jj) {
      int j = j0 + jj;
      if (j < steps) {
        win[(j + 15) & 15] = xr[(size_t)(t0 + j + 15) * 128];
        float ax = b0, ay = b0, az = b0, aw = b0;
#pragma unroll
        for (int k = 0; k < 16; ++k) {
          float4 v = win[(j + k) & 15];
          float wk = wgt[k];
          ax += wk * v.x; ay += wk * v.y; az += wk * v.z; aw += wk * v.w;
        }
        f16x4 o; o.x = (f16)ax; o.y = (f16)ay; o.z = (f16)az; o.w = (f16)aw;
        *(f16x4*)(sp + (size_t)j * 512) = o;
      }
    }
  }
}

// ---------------------------------------------------------------------------
// Xp = syn @ K + bias  (fp32 result written into d_out, overwritten later by
// the recurrent kernel in place).  128x128 tile, BK=32, mfma 16x16x32 f16.
// ---------------------------------------------------------------------------
__global__ __launch_bounds__(256) void k_gemm(
    const f16* __restrict__ syn, const f16* __restrict__ Kt,
    const float* __restrict__ bias, float* __restrict__ out) {
  int bid = blockIdx.x;
  size_t m0 = (size_t)(bid >> 2) * 128;
  int n0 = (bid & 3) * 128;
  int tid = threadIdx.x;
  int wave = tid >> 6, lane = tid & 63;
  int q = lane >> 4, l15 = lane & 15;
  __shared__ f16 lA[128 * 32];
  __shared__ f16 lB[128 * 32];
  f32x4 acc[8][2] = {};
  int s0 = tid, s1 = tid + 256;
  int rA0 = s0 >> 2, cA0 = (s0 & 3) * 8;
  int rA1 = s1 >> 2, cA1 = (s1 & 3) * 8;
  for (int k0 = 0; k0 < 512; k0 += 32) {
    f16x8 a0 = *(const f16x8*)(syn + (m0 + rA0) * 512 + k0 + cA0);
    f16x8 a1 = *(const f16x8*)(syn + (m0 + rA1) * 512 + k0 + cA1);
    f16x8 b0 = *(const f16x8*)(Kt + (size_t)(n0 + rA0) * 512 + k0 + cA0);
    f16x8 b1 = *(const f16x8*)(Kt + (size_t)(n0 + rA1) * 512 + k0 + cA1);
    __syncthreads();                       // previous tile fully consumed
    *(f16x8*)(lA + s0 * 8) = a0;  *(f16x8*)(lA + s1 * 8) = a1;
    *(f16x8*)(lB + s0 * 8) = b0;  *(f16x8*)(lB + s1 * 8) = b1;
    __syncthreads();
    f16x8 bf[2];
#pragma unroll
    for (int j = 0; j < 2; ++j)
      bf[j] = *(const f16x8*)(lB + (wave * 32 + j * 16 + l15) * 32 + q * 8);
#pragma unroll
    for (int i = 0; i < 8; ++i) {
      f16x8 af = *(const f16x8*)(lA + (i * 16 + l15) * 32 + q * 8);
      acc[i][0] = __builtin_amdgcn_mfma_f32_16x16x32_f16(af, bf[0], acc[i][0], 0, 0, 0);
      acc[i][1] = __builtin_amdgcn_mfma_f32_16x16x32_f16(af, bf[1], acc[i][1], 0, 0, 0);
    }
  }
#pragma unroll
  for (int j = 0; j < 2; ++j) {
    int col = n0 + wave * 32 + j * 16 + l15;
    float bv = bias[col];
#pragma unroll
    for (int i = 0; i < 8; ++i) {
      size_t row = m0 + i * 16 + q * 4;
#pragma unroll
      for (int r = 0; r < 4; ++r)
        out[(row + r) * 512 + col] = acc[i][j][r] + bv;
    }
  }
}

// ---------------------------------------------------------------------------
// Sequential recurrence.  256 blocks x 1 batch, 1024 threads = 16 waves
// (4 waves/SIMD -- the round-9 lever).  At full clock (FLOP cross-check:
// R8 ran 1,065 TF = 45% of ceiling), the step is MFMA-pipe busy 2,483cy/SIMD
// out of 4,848cy; the gap is per-wave serial glue (epilogue chain, LDS
// latency, barrier skew) that 2 waves/SIMD cannot hide.  4 waves/SIMD keeps
// the same per-SIMD MFMA issue (4 waves x 32 MFMAs) and hides the glue.
//  - Wave owns 32 output units (nt=0,1): rs[11][2] = 88 regs (kk0..10),
//    R4 tile kk11..14 (128KB swizzled LDS), kk15 streamed from L2.
//    Register budget ~125 <= 128 (required for 4 waves/SIMD;
//    __launch_bounds__(1024,4) pins the allocator).
//  - af path: R5's zero-region trick (no v_and masks): l15==0 lanes read the
//    real state fragment, l15>0 lanes read a permanent zero region whose
//    16B-unit offset differs by 4 (mod 8) from both state buffers -> the
//    8-address broadcast read is bank-conflict-free.
//  - State: row 0 only, double-buffered in SRZ; pi-layout write is f16x2 at
//    (w>>1)*64 + l15*4 + 2*(w&1) (units nt=0,1 adjacent by construction).
// One raw s_barrier per step (lgkmcnt drain only; global stores are
// disjoint-address, never drained in-loop).
// ---------------------------------------------------------------------------
__global__ __launch_bounds__(1024, 4) void k_rnn(
    const f16* __restrict__ Rt, float* __restrict__ io) {
  int b = blockIdx.x;             // one batch per block
  int tid = threadIdx.x, wave = tid >> 6, lane = tid & 63;
  int q = lane >> 4, l15 = lane & 15;
  __shared__ f16 R4[4 * 512 * 32];           // kk 11..14, swizzled (128KB)
  // SRZ: [SR0 512][SR1 512][pad 32][Z 544] halves.  Zero region at offset
  // 1056 halfs = 132 sixteen-B units; 132%8=4 and (132-64)%8=4 -> disjoint
  // bank-quads from both state buffers.
  __shared__ __align__(64) f16 SRZ[1600];

  // ---- stage R kk11..14 into LDS, swizzle: 16B slot c -> c ^ (row&3) ----
  {
    int row = tid & 511;
    int h = tid >> 9;                // 0/1: stage groups {0,1} / {2,3}
    const f16x8* src = (const f16x8*)(Rt + (size_t)row * 512 + 11 * 32);
#pragma unroll
    for (int gg = 0; gg < 2; ++gg) {
      int g = h * 2 + gg;
      char* dst = (char*)R4 + g * 32768 + row * 64;
#pragma unroll
      for (int c = 0; c < 4; ++c)
        *(f16x8*)(dst + ((c * 16) ^ ((row & 3) << 4))) = src[g * 4 + c];
    }
    for (int i = tid; i < 1600; i += 1024) SRZ[i] = (f16)0.f;
  }

  int row0 = wave * 32 + l15;        // first owned unit (nt=0); nt=1 at +16
  // ---- kk0..10 register-resident: rs[11][2] = 88 regs ----
  const f16* rbase = Rt + (size_t)row0 * 512 + q * 8;
  f16x8 rs[11][2];
#pragma unroll
  for (int kk = 0; kk < 11; ++kk)
#pragma unroll
    for (int nt = 0; nt < 2; ++nt)
      rs[kk][nt] = *(const f16x8*)(rbase + (size_t)nt * 8192 + kk * 32);

  // per-lane R4 read base: row = row0 (+nt*16), slot q ^ (l15&3)
  const char* r4base = (const char*)R4 + row0 * 64
                       + ((q * 16) ^ ((l15 & 3) << 4));

  bool l0 = (l15 == 0);
  const f16* zb = SRZ + 1056 + q * 8;            // zero region (never written)
  const f16* pc = l0 ? (SRZ + q * 8)       : zb; // af base, current state buf
  const f16* pn = l0 ? (SRZ + 512 + q * 8) : zb; // af base, next state buf
  int wpos = (wave >> 1) * 64 + l15 * 4 + 2 * (wave & 1);
  f16* wc = SRZ + 512 + wpos;        // state write when reading SR0
  f16* wn = SRZ + wpos;              // state write when reading SR1

  bool active = (q == 0);            // only C/D row 0 is real
  unsigned ioff = (unsigned)b * (TP * 512u) + (unsigned)row0;
  float xp0 = io[ioff], xp1 = io[ioff + 16u];

  __syncthreads();

  for (int t = 0; t < TP; ++t) {
    // ---- issue kk15 L2 stream at step-top (consumed last) ----
    f16x8 sw0 = *(const f16x8*)(rbase + 15 * 32);
    f16x8 sw1 = *(const f16x8*)(rbase + 8192 + 15 * 32);
    f32x4 a0 = {}, a1 = {};
    // ---- kk 0..10: zero-region broadcast af + register-resident B ----
#pragma unroll
    for (int kk = 0; kk < 11; ++kk) {
      f16x8 af = *(const f16x8*)(pc + kk * 32);
      a0 = __builtin_amdgcn_mfma_f32_16x16x32_f16(af, rs[kk][0], a0, 0, 0, 0);
      a1 = __builtin_amdgcn_mfma_f32_16x16x32_f16(af, rs[kk][1], a1, 0, 0, 0);
    }
    // ---- kk 11..14: B from LDS tile (swizzled) ----
#pragma unroll
    for (int g = 0; g < 4; ++g) {
      f16x8 bf0 = *(const f16x8*)(r4base + g * 32768);
      f16x8 bf1 = *(const f16x8*)(r4base + g * 32768 + 1024);
      f16x8 af  = *(const f16x8*)(pc + (11 + g) * 32);
      a0 = __builtin_amdgcn_mfma_f32_16x16x32_f16(af, bf0, a0, 0, 0, 0);
      a1 = __builtin_amdgcn_mfma_f32_16x16x32_f16(af, bf1, a1, 0, 0, 0);
    }
    // ---- kk 15: streamed B ----
    {
      f16x8 af = *(const f16x8*)(pc + 15 * 32);
      a0 = __builtin_amdgcn_mfma_f32_16x16x32_f16(af, sw0, a0, 0, 0, 0);
      a1 = __builtin_amdgcn_mfma_f32_16x16x32_f16(af, sw1, a1, 0, 0, 0);
    }
    // ---- epilogue: row 0 only; n -> io, new state -> next buffer ----
    {
      float o0 = a0[0] + xp0;
      float o1 = a1[0] + xp1;
      float n0 = __builtin_amdgcn_rcpf(1.f + __builtin_amdgcn_exp2f(-4.3280850f * o0));
      float n1 = __builtin_amdgcn_rcpf(1.f + __builtin_amdgcn_exp2f(-4.3280850f * o1));
      float g0 = __builtin_amdgcn_rcpf(1.f + __builtin_amdgcn_exp2f((2.f * n0 - 1.f) * 1.4426950f));
      float g1 = __builtin_amdgcn_rcpf(1.f + __builtin_amdgcn_exp2f((2.f * n1 - 1.f) * 1.4426950f));
      if (active) {
        io[ioff]       = n0;                    // n overwrites Xp
        io[ioff + 16u] = n1;
        f16x2 sv; sv.x = (f16)(o0 * g0); sv.y = (f16)(o1 * g1);
        *(f16x2*)wc = sv;                       // pi-layout state write
      }
    }
    ioff += 512u;
    if (t < TP - 1) {                           // prefetch Xp[t+1]
      xp0 = io[ioff]; xp1 = io[ioff + 16u];
    }
    // Single barrier per step: drain LDS (state write) only; global stores
    // are disjoint-address and never drained in-loop.
    asm volatile("s_waitcnt lgkmcnt(0)\n\ts_barrier" ::: "memory");
    const f16* tp = pc; pc = pn; pn = tp;
    f16* tw = wc; wc = wn; wn = tw;
  }
}

// ---------------------------------------------------------------------------
extern "C" void kernel_launch(void* const* d_in, const int* in_sizes, int n_in,
                              void* d_out, int out_size, void* d_ws, size_t ws_size,
                              hipStream_t stream) {
  (void)in_sizes; (void)n_in; (void)out_size; (void)ws_size;
  const float* x     = (const float*)d_in[0];
  const float* psc_w = (const float*)d_in[1];
  const float* psc_b = (const float*)d_in[2];
  const float* kern  = (const float*)d_in[3];
  const float* rec   = (const float*)d_in[4];
  const float* bias  = (const float*)d_in[5];
  float* out = (float*)d_out;
  char* ws = (char*)d_ws;
  // ws layout: syn f16 (258304*512*2 = 264,503,296 B) | Kt f16 512KB | Rt f16 512KB
  f16* syn = (f16*)ws;
  f16* Kt  = (f16*)(ws + 264503296ull);
  f16* Rt  = (f16*)(ws + 265027584ull);

  k_convert<<<2048, 256, 0, stream>>>(kern, rec, Kt, Rt);
  k_conv   <<<2048, 256, 0, stream>>>(x, psc_w, psc_b, syn);
  k_gemm   <<<2018 * 4, 256, 0, stream>>>(syn, Kt, bias, out);
  k_rnn    <<<256, 1024, 0, stream>>>(Rt, out);
}